// Round 4
// baseline (184.810 us; speedup 1.0000x reference)
//
#include <hip/hip_runtime.h>

// SWD18: per-feature cyclic window-of-5 sort (verified absmax=0 through R10):
// for column i, sort rows {5m + (i%5) + j mod L, j=0..4} ascending, in place.
// q, k are dead inputs.
//
// R10 post-mortem (counters): FETCH 36.6 MB << logical reads -> input is
// L3-resident, read amp is ~free. hbm 2.5 TB/s, VALU 15%, occ 35%, VGPR=32
// -> latency-bound; compiler sank the ring loads, each group paid a full
// load round trip; too few memory ops in flight per thread.
//
// R11 failed to compile: __builtin_nontemporal_store rejects HIP float4
// (HIP_vector_type class). R12 = R11 with clang native ext_vector_type(4)
// (accepted by the builtin, has .x/.y/.z/.w swizzles). Algorithm unchanged.
//
// Thread = (window w, column quad c0): 14 native-float4 loads of the
// verified 14-row A/B footprint (rows R0-5..R0+8), verified window-select +
// 9-comparator sorts + output mux PER COMPONENT (rc = (c0+j)%5), 5 float4
// NT stores (rows R0..R0+4, never wrap). 19 VMEM @ 1KB/wave-instr per 20
// output floats (R10: 110 VMEM @ 256B). All in[] indices compile-time.
// Predicted kernel 15-18 us, VALUBusy ~30%, VGPR ~96-112, bench ~156-160.

constexpr int L   = 4000;
constexpr int D   = 512;
constexpr int NW  = L / 5;        // 800 windows per batch
constexpr int WPB = 2;            // windows per block
constexpr int NBX = NW / WPB;     // 400 blocks in x per batch

typedef float f4 __attribute__((ext_vector_type(4)));

// optimal 9-comparator sorting network for 5, ascending
#define CE(a, b) { float lo_ = fminf(a, b); float hi_ = fmaxf(a, b); (a) = lo_; (b) = hi_; }

__global__ __launch_bounds__(256, 4)
void swd18_f4(const float* __restrict__ v, float* __restrict__ out) {
    // ---- bijective XCD-chunk swizzle (nwg = 3200, nwg%8 == 0 -> rm = 0) ----
    const int nwg = gridDim.x * gridDim.y;
    const int lid = blockIdx.x + gridDim.x * blockIdx.y;   // dispatch order
    const int qq  = nwg >> 3;
    const int xcd = lid & 7;
    const int pos = lid >> 3;
    const int nid = xcd * qq + pos;

    const int b  = nid / NBX;
    const int bx = nid % NBX;

    const int w  = WPB * bx + (threadIdx.x >> 7);  // window index (wave-uniform)
    const int q  = threadIdx.x & 127;              // column quad 0..127
    const int c0 = q << 2;                         // first column of quad
    const int R0 = 5 * w;                          // output rows R0..R0+4

    const f4* __restrict__ vb4 = (const f4*)(v   + (size_t)b * (L * D));
    f4*       __restrict__ ob4 = (f4*)      (out + (size_t)b * (L * D));

    // ---- 14 f4 loads: rows R0-5 .. R0+8, cyclic only at batch edges ----
    // Row wave-uniform -> 64 lanes x 16B = 1KB contiguous per instruction.
    f4 in[14];
#pragma unroll
    for (int r = 0; r < 14; ++r) {
        int row = R0 - 5 + r;
        if (row < 0)  row += L;                    // w==0
        if (row >= L) row -= L;                    // w==NW-1
        in[r] = vb4[(size_t)row * (D / 4) + q];
    }

    const int rc0 = c0 % 5;
    f4 o0, o1, o2, o3, o4;

    // Per component: verified R7/R8 A/B window select + sorts + output mux.
    // p[n] == in[n].F ; out rows R0+t get (t < rc) ? A[t+5-rc] : B[t-rc].
#define COMP(J, F) do {                                                         \
    int rcj = rc0 + (J); if (rcj >= 5) rcj -= 5;                                \
    const bool e0 = rcj == 0, e1 = rcj == 1, e2 = rcj == 2, e3 = rcj == 3;      \
    float A0 = e0 ? in[0].F : e1 ? in[1].F : e2 ? in[2].F : e3 ? in[3].F : in[4].F;   \
    float A1 = e0 ? in[1].F : e1 ? in[2].F : e2 ? in[3].F : e3 ? in[4].F : in[5].F;   \
    float A2 = e0 ? in[2].F : e1 ? in[3].F : e2 ? in[4].F : e3 ? in[5].F : in[6].F;   \
    float A3 = e0 ? in[3].F : e1 ? in[4].F : e2 ? in[5].F : e3 ? in[6].F : in[7].F;   \
    float A4 = e0 ? in[4].F : e1 ? in[5].F : e2 ? in[6].F : e3 ? in[7].F : in[8].F;   \
    float B0 = e0 ? in[5].F : e1 ? in[6].F : e2 ? in[7].F : e3 ? in[8].F : in[9].F;   \
    float B1 = e0 ? in[6].F : e1 ? in[7].F : e2 ? in[8].F : e3 ? in[9].F : in[10].F;  \
    float B2 = e0 ? in[7].F : e1 ? in[8].F : e2 ? in[9].F : e3 ? in[10].F : in[11].F; \
    float B3 = e0 ? in[8].F : e1 ? in[9].F : e2 ? in[10].F : e3 ? in[11].F : in[12].F;\
    float B4 = e0 ? in[9].F : e1 ? in[10].F : e2 ? in[11].F : e3 ? in[12].F : in[13].F;\
    CE(A0, A1) CE(A3, A4) CE(A2, A4) CE(A2, A3) CE(A1, A4)                      \
    CE(A0, A3) CE(A0, A2) CE(A1, A3) CE(A1, A2)                                 \
    CE(B0, B1) CE(B3, B4) CE(B2, B4) CE(B2, B3) CE(B1, B4)                      \
    CE(B0, B3) CE(B0, B2) CE(B1, B3) CE(B1, B2)                                 \
    o0.F = e0 ? B0 : e1 ? A4 : e2 ? A3 : e3 ? A2 : A1;                          \
    o1.F = e0 ? B1 : e1 ? B0 : e2 ? A4 : e3 ? A3 : A2;                          \
    o2.F = e0 ? B2 : e1 ? B1 : e2 ? B0 : e3 ? A4 : A3;                          \
    o3.F = e0 ? B3 : e1 ? B2 : e2 ? B1 : e3 ? B0 : A4;                          \
    o4.F = e0 ? B4 : e1 ? B3 : e2 ? B2 : e3 ? B1 : B0;                          \
} while (0)

    COMP(0, x);
    COMP(1, y);
    COMP(2, z);
    COMP(3, w);
#undef COMP

    // ---- 5 f4 NT stores: rows R0..R0+4 (never wrap), 1KB/wave-instr ----
    f4* o = ob4 + (size_t)R0 * (D / 4) + q;
    __builtin_nontemporal_store(o0, o + 0 * (D / 4));
    __builtin_nontemporal_store(o1, o + 1 * (D / 4));
    __builtin_nontemporal_store(o2, o + 2 * (D / 4));
    __builtin_nontemporal_store(o3, o + 3 * (D / 4));
    __builtin_nontemporal_store(o4, o + 4 * (D / 4));
}

#undef CE

extern "C" void kernel_launch(void* const* d_in, const int* in_sizes, int n_in,
                              void* d_out, int out_size, void* d_ws, size_t ws_size,
                              hipStream_t stream) {
    // setup_inputs order: q, k, v — only v is used by the reference forward.
    const float* v = (const float*)d_in[2];
    float* out = (float*)d_out;

    const int B = in_sizes[2] / (L * D);           // 8 for the bench shape
    dim3 grid(NBX, B);                             // 400 x 8 = 3200 blocks of 256
    swd18_f4<<<grid, dim3(256), 0, stream>>>(v, out);
}

// Round 5
// 182.378 us; speedup vs baseline: 1.0133x; 1.0133x over previous
//
#include <hip/hip_runtime.h>

// SWD18: per-feature cyclic window-of-5 sort (verified absmax=0 through R12):
// for column i, sort rows {5m + (i%5) + j mod L, j=0..4} ascending, in place.
// q, k are dead inputs.
//
// R12 post-mortem: VGPR_Count=32 again (14 resident f4 needs >=56) -> the
// compiler SCALARIZED the dwordx4 loads (each load's only uses are
// extractelements feeding the muxes; VectorCombine narrows to dword loads)
// and sank each component slice next to its COMP. 56 serialized 4B-per-lane
// loads at 16B stride = the same latency pathology as R10/R6, dur 42.6 us,
// VALU 24%, hbm 29% -> latency-bound, not traffic-bound (FETCH 32MB: L3
// holds the input).
//
// R13: pin the vectors. asm volatile("" : "+v"(in[r])) right after the load
// loop gives every <4 x float> load a VECTOR use (can't be scalarized) and
// forces all 14 global_load_dwordx4 to issue back-to-back into registers
// before any compute: 14 loads in flight per thread, one vmcnt wall instead
// of 56 sunk round trips. Everything else identical to R12.
// Prediction: VGPR 32 -> ~90-110 (proof the pin landed; if still 32 ->
// LDS-staging next), kernel 42.6 -> 15-20 us, bench ~158-165 us.

constexpr int L   = 4000;
constexpr int D   = 512;
constexpr int NW  = L / 5;        // 800 windows per batch
constexpr int WPB = 2;            // windows per block
constexpr int NBX = NW / WPB;     // 400 blocks in x per batch

typedef float f4 __attribute__((ext_vector_type(4)));

// optimal 9-comparator sorting network for 5, ascending
#define CE(a, b) { float lo_ = fminf(a, b); float hi_ = fmaxf(a, b); (a) = lo_; (b) = hi_; }

__global__ __launch_bounds__(256, 4)
void swd18_f4pin(const float* __restrict__ v, float* __restrict__ out) {
    // ---- bijective XCD-chunk swizzle (nwg = 3200, nwg%8 == 0 -> rm = 0) ----
    const int nwg = gridDim.x * gridDim.y;
    const int lid = blockIdx.x + gridDim.x * blockIdx.y;   // dispatch order
    const int qq  = nwg >> 3;
    const int xcd = lid & 7;
    const int pos = lid >> 3;
    const int nid = xcd * qq + pos;

    const int b  = nid / NBX;
    const int bx = nid % NBX;

    const int w  = WPB * bx + (threadIdx.x >> 7);  // window index (wave-uniform)
    const int q  = threadIdx.x & 127;              // column quad 0..127
    const int c0 = q << 2;                         // first column of quad
    const int R0 = 5 * w;                          // output rows R0..R0+4

    const f4* __restrict__ vb4 = (const f4*)(v   + (size_t)b * (L * D));
    f4*       __restrict__ ob4 = (f4*)      (out + (size_t)b * (L * D));

    // ---- 14 f4 loads: rows R0-5 .. R0+8, cyclic only at batch edges ----
    // Row wave-uniform -> 64 lanes x 16B = 1KB contiguous per instruction.
    f4 in[14];
#pragma unroll
    for (int r = 0; r < 14; ++r) {
        int row = R0 - 5 + r;
        if (row < 0)  row += L;                    // w==0
        if (row >= L) row -= L;                    // w==NW-1
        in[r] = vb4[(size_t)row * (D / 4) + q];
    }
    // Pin: vector use for each load (defeats VectorCombine scalarization,
    // R10/R12 VGPR=32 pathology) + forces all 14 dwordx4 resident here.
#pragma unroll
    for (int r = 0; r < 14; ++r)
        asm volatile("" : "+v"(in[r]));

    const int rc0 = c0 % 5;
    f4 o0, o1, o2, o3, o4;

    // Per component: verified R7/R8 A/B window select + sorts + output mux.
    // p[n] == in[n].F ; out rows R0+t get (t < rc) ? A[t+5-rc] : B[t-rc].
#define COMP(J, F) do {                                                         \
    int rcj = rc0 + (J); if (rcj >= 5) rcj -= 5;                                \
    const bool e0 = rcj == 0, e1 = rcj == 1, e2 = rcj == 2, e3 = rcj == 3;      \
    float A0 = e0 ? in[0].F : e1 ? in[1].F : e2 ? in[2].F : e3 ? in[3].F : in[4].F;   \
    float A1 = e0 ? in[1].F : e1 ? in[2].F : e2 ? in[3].F : e3 ? in[4].F : in[5].F;   \
    float A2 = e0 ? in[2].F : e1 ? in[3].F : e2 ? in[4].F : e3 ? in[5].F : in[6].F;   \
    float A3 = e0 ? in[3].F : e1 ? in[4].F : e2 ? in[5].F : e3 ? in[6].F : in[7].F;   \
    float A4 = e0 ? in[4].F : e1 ? in[5].F : e2 ? in[6].F : e3 ? in[7].F : in[8].F;   \
    float B0 = e0 ? in[5].F : e1 ? in[6].F : e2 ? in[7].F : e3 ? in[8].F : in[9].F;   \
    float B1 = e0 ? in[6].F : e1 ? in[7].F : e2 ? in[8].F : e3 ? in[9].F : in[10].F;  \
    float B2 = e0 ? in[7].F : e1 ? in[8].F : e2 ? in[9].F : e3 ? in[10].F : in[11].F; \
    float B3 = e0 ? in[8].F : e1 ? in[9].F : e2 ? in[10].F : e3 ? in[11].F : in[12].F;\
    float B4 = e0 ? in[9].F : e1 ? in[10].F : e2 ? in[11].F : e3 ? in[12].F : in[13].F;\
    CE(A0, A1) CE(A3, A4) CE(A2, A4) CE(A2, A3) CE(A1, A4)                      \
    CE(A0, A3) CE(A0, A2) CE(A1, A3) CE(A1, A2)                                 \
    CE(B0, B1) CE(B3, B4) CE(B2, B4) CE(B2, B3) CE(B1, B4)                      \
    CE(B0, B3) CE(B0, B2) CE(B1, B3) CE(B1, B2)                                 \
    o0.F = e0 ? B0 : e1 ? A4 : e2 ? A3 : e3 ? A2 : A1;                          \
    o1.F = e0 ? B1 : e1 ? B0 : e2 ? A4 : e3 ? A3 : A2;                          \
    o2.F = e0 ? B2 : e1 ? B1 : e2 ? B0 : e3 ? A4 : A3;                          \
    o3.F = e0 ? B3 : e1 ? B2 : e2 ? B1 : e3 ? B0 : A4;                          \
    o4.F = e0 ? B4 : e1 ? B3 : e2 ? B2 : e3 ? B1 : B0;                          \
} while (0)

    COMP(0, x);
    COMP(1, y);
    COMP(2, z);
    COMP(3, w);
#undef COMP

    // ---- 5 f4 NT stores: rows R0..R0+4 (never wrap), 1KB/wave-instr ----
    f4* o = ob4 + (size_t)R0 * (D / 4) + q;
    __builtin_nontemporal_store(o0, o + 0 * (D / 4));
    __builtin_nontemporal_store(o1, o + 1 * (D / 4));
    __builtin_nontemporal_store(o2, o + 2 * (D / 4));
    __builtin_nontemporal_store(o3, o + 3 * (D / 4));
    __builtin_nontemporal_store(o4, o + 4 * (D / 4));
}

#undef CE

extern "C" void kernel_launch(void* const* d_in, const int* in_sizes, int n_in,
                              void* d_out, int out_size, void* d_ws, size_t ws_size,
                              hipStream_t stream) {
    // setup_inputs order: q, k, v — only v is used by the reference forward.
    const float* v = (const float*)d_in[2];
    float* out = (float*)d_out;

    const int B = in_sizes[2] / (L * D);           // 8 for the bench shape
    dim3 grid(NBX, B);                             // 400 x 8 = 3200 blocks of 256
    swd18_f4pin<<<grid, dim3(256), 0, stream>>>(v, out);
}